// Round 1
// baseline (9196.397 us; speedup 1.0000x reference)
//
#include <hip/hip_runtime.h>
#include <hip/hip_bf16.h>

// ---------------- problem constants ----------------
constexpr int B = 65536;
constexpr int D = 512;
constexpr int E = 8;
constexpr int H = 2048;

// ---------------- tile config ----------------
constexpr int MT = 32;          // tokens per block tile
constexpr int HC = 64;          // H-chunk per iteration
constexpr int XS_ST  = D + 8;   // xs row stride in shorts (pad -> 2-way LDS conflicts only)
constexpr int W1T_ST = D + 8;   // w1T row (per h-col) stride over k=D
constexpr int W2T_ST = HC + 8;  // w2T row (per d-col) stride over k=HC
constexpr int HT_ST  = HC + 8;  // ht row (per token) stride over h-chunk

typedef __bf16 bf16x8 __attribute__((ext_vector_type(8)));
typedef float  f32x4  __attribute__((ext_vector_type(4)));

__device__ __forceinline__ unsigned short f2bf(float f) {
    unsigned u = __float_as_uint(f);
    u += 0x7FFFu + ((u >> 16) & 1u);   // round-to-nearest-even
    return (unsigned short)(u >> 16);
}

// ---------------- kernel 1: router ----------------
// one wave per token: logits = x @ rw + rb; top-2; renormalized weights;
// atomic append into per-expert (token, weight) lists.
__global__ __launch_bounds__(256) void router_kernel(
    const float* __restrict__ x, const float* __restrict__ rw,
    const float* __restrict__ rb, unsigned* __restrict__ cnt,
    unsigned* __restrict__ tok_list, float* __restrict__ w_list) {
    const int lane = threadIdx.x & 63;
    const int t = blockIdx.x * 4 + (threadIdx.x >> 6);
    const float* xr = x + (size_t)t * D;

    float acc[E];
#pragma unroll
    for (int e = 0; e < E; ++e) acc[e] = 0.f;
#pragma unroll
    for (int i = 0; i < D / 64; ++i) {
        const int d = lane + 64 * i;
        const float xv = xr[d];
        const float4 wa = *(const float4*)(rw + (size_t)d * E);
        const float4 wb = *(const float4*)(rw + (size_t)d * E + 4);
        acc[0] += xv * wa.x; acc[1] += xv * wa.y;
        acc[2] += xv * wa.z; acc[3] += xv * wa.w;
        acc[4] += xv * wb.x; acc[5] += xv * wb.y;
        acc[6] += xv * wb.z; acc[7] += xv * wb.w;
    }
#pragma unroll
    for (int off = 32; off > 0; off >>= 1) {
#pragma unroll
        for (int e = 0; e < E; ++e) acc[e] += __shfl_down(acc[e], off, 64);
    }
    if (lane == 0) {
#pragma unroll
        for (int e = 0; e < E; ++e) acc[e] += rb[e];
        int e0 = 0; float l0 = acc[0];
#pragma unroll
        for (int e = 1; e < E; ++e) if (acc[e] > l0) { l0 = acc[e]; e0 = e; }
        int e1 = -1; float l1 = -3.4e38f;
#pragma unroll
        for (int e = 0; e < E; ++e) if (e != e0 && acc[e] > l1) { l1 = acc[e]; e1 = e; }
        // renormalized top-2 softmax weights == softmax over {l0, l1}
        const float w0 = 1.f / (1.f + __expf(l1 - l0));
        const float w1v = 1.f - w0;
        const unsigned s0 = atomicAdd(&cnt[e0], 1u);
        tok_list[(size_t)e0 * B + s0] = (unsigned)t;
        w_list[(size_t)e0 * B + s0] = w0;
        const unsigned s1 = atomicAdd(&cnt[e1], 1u);
        tok_list[(size_t)e1 * B + s1] = (unsigned)t;
        w_list[(size_t)e1 * B + s1] = w1v;
    }
}

// ---------------- kernel 2: fused expert FFN ----------------
// block = (expert e, tile of MT gathered tokens). Loops H in chunks of HC:
//   phase1: ht = relu(xs @ w1[:, chunk] + b1[chunk])   (MFMA 16x16x32 bf16)
//   phase2: acc += ht @ w2[chunk, :]                   (MFMA)
// epilogue: out[token] += weight * (acc + b2)   (atomic fp32)
struct alignas(16) Smem {
    unsigned short xs[MT * XS_ST];      // 33280 B
    unsigned short wb[36864];           // 73728 B: w1T [HC][W1T_ST] or w2T [D][W2T_ST]
    unsigned short ht[MT * HT_ST];      // 4608 B
    int   toks[MT];
    float wgts[MT];
};

__global__ __launch_bounds__(256) void ffn_kernel(
    const float* __restrict__ x,
    const float* __restrict__ w1, const float* __restrict__ b1,
    const float* __restrict__ w2, const float* __restrict__ b2,
    float* __restrict__ out,
    const unsigned* __restrict__ cnt,
    const unsigned* __restrict__ tok_list, const float* __restrict__ w_list) {
    __shared__ Smem sm;

    const int tile = blockIdx.x;
    const int e = blockIdx.y;
    const unsigned ncnt = cnt[e];
    if ((unsigned)(tile * MT) >= ncnt) return;

    const int tid = threadIdx.x;
    const int wv = tid >> 6;           // wave 0..3
    const int lane = tid & 63;
    const int ln = lane & 15;
    const int q = lane >> 4;

    // ---- stage token ids / weights ----
    if (tid < MT) {
        const int li = tile * MT + tid;
        if (li < (int)ncnt) {
            sm.toks[tid] = (int)tok_list[(size_t)e * B + li];
            sm.wgts[tid] = w_list[(size_t)e * B + li];
        } else {
            sm.toks[tid] = (int)tok_list[(size_t)e * B + tile * MT];
            sm.wgts[tid] = 0.f;
        }
    }

    // ---- stage xs: MT rows of x (gathered), fp32 -> bf16 ----
    {
        const int r = tid >> 3;        // row 0..31
        const int c8 = tid & 7;
        const int li = tile * MT + r;
        const unsigned tok = (li < (int)ncnt) ? tok_list[(size_t)e * B + li]
                                              : tok_list[(size_t)e * B + tile * MT];
        const float* src = x + (size_t)tok * D;
#pragma unroll
        for (int i = 0; i < 16; ++i) {
            const int d = (c8 + 8 * i) * 4;
            const float4 v = *(const float4*)(src + d);
            uint2 pk;
            pk.x = (unsigned)f2bf(v.x) | ((unsigned)f2bf(v.y) << 16);
            pk.y = (unsigned)f2bf(v.z) | ((unsigned)f2bf(v.w) << 16);
            *(uint2*)(sm.xs + r * XS_ST + d) = pk;
        }
    }

    f32x4 acc[2][8];
#pragma unroll
    for (int mt = 0; mt < 2; ++mt)
#pragma unroll
        for (int nt = 0; nt < 8; ++nt) acc[mt][nt] = (f32x4){0.f, 0.f, 0.f, 0.f};

    for (int hc = 0; hc < H; hc += HC) {
        __syncthreads();   // xs ready (iter 0); wb free from prev phase2

        // ---- stage w1 chunk transposed: w1T[n(h)][k(d)] ----
        {
            const int nf = tid & 15;       // float4 column group within chunk
            const int d0 = tid >> 4;       // 0..15
            const float* src = w1 + (size_t)e * D * H + hc + nf * 4;
#pragma unroll 4
            for (int i = 0; i < 32; ++i) {
                const int d = d0 + 16 * i;
                const float4 v = *(const float4*)(src + (size_t)d * H);
                sm.wb[(nf * 4 + 0) * W1T_ST + d] = f2bf(v.x);
                sm.wb[(nf * 4 + 1) * W1T_ST + d] = f2bf(v.y);
                sm.wb[(nf * 4 + 2) * W1T_ST + d] = f2bf(v.z);
                sm.wb[(nf * 4 + 3) * W1T_ST + d] = f2bf(v.w);
            }
        }
        __syncthreads();

        // ---- phase1: ht = relu(xs @ w1chunk + b1), wave wv covers h-cols [wv*16, wv*16+16) ----
        {
            f32x4 c0 = (f32x4){0.f, 0.f, 0.f, 0.f};
            f32x4 c1 = (f32x4){0.f, 0.f, 0.f, 0.f};
#pragma unroll
            for (int ks = 0; ks < D / 32; ++ks) {
                const bf16x8 a0 = *(const bf16x8*)(sm.xs + ln * XS_ST + ks * 32 + q * 8);
                const bf16x8 a1 = *(const bf16x8*)(sm.xs + (16 + ln) * XS_ST + ks * 32 + q * 8);
                const bf16x8 bb = *(const bf16x8*)(sm.wb + (wv * 16 + ln) * W1T_ST + ks * 32 + q * 8);
                c0 = __builtin_amdgcn_mfma_f32_16x16x32_bf16(a0, bb, c0, 0, 0, 0);
                c1 = __builtin_amdgcn_mfma_f32_16x16x32_bf16(a1, bb, c1, 0, 0, 0);
            }
            const float b1v = b1[(size_t)e * H + hc + wv * 16 + ln];
#pragma unroll
            for (int r = 0; r < 4; ++r) {
                float h0 = c0[r] + b1v; h0 = h0 > 0.f ? h0 : 0.f;
                float h1 = c1[r] + b1v; h1 = h1 > 0.f ? h1 : 0.f;
                sm.ht[(q * 4 + r) * HT_ST + wv * 16 + ln] = f2bf(h0);
                sm.ht[(16 + q * 4 + r) * HT_ST + wv * 16 + ln] = f2bf(h1);
            }
        }
        __syncthreads();   // phase1 done reading wb, ht written

        // ---- stage w2 chunk transposed: w2T[n(d)][k(h)] ----
        {
#pragma unroll 4
            for (int i = 0; i < 32; ++i) {
                const int idx = tid + 256 * i;      // 0..8191
                const int k = idx >> 7;             // 0..63
                const int d4 = idx & 127;
                const float4 v = *(const float4*)(w2 + ((size_t)(e * H + hc + k)) * D + d4 * 4);
                sm.wb[(d4 * 4 + 0) * W2T_ST + k] = f2bf(v.x);
                sm.wb[(d4 * 4 + 1) * W2T_ST + k] = f2bf(v.y);
                sm.wb[(d4 * 4 + 2) * W2T_ST + k] = f2bf(v.z);
                sm.wb[(d4 * 4 + 3) * W2T_ST + k] = f2bf(v.w);
            }
        }
        __syncthreads();

        // ---- phase2: acc += ht @ w2chunk; wave wv covers d-cols [wv*128, wv*128+128) ----
#pragma unroll
        for (int ks = 0; ks < HC / 32; ++ks) {
            const bf16x8 a0 = *(const bf16x8*)(sm.ht + ln * HT_ST + ks * 32 + q * 8);
            const bf16x8 a1 = *(const bf16x8*)(sm.ht + (16 + ln) * HT_ST + ks * 32 + q * 8);
#pragma unroll
            for (int nt = 0; nt < 8; ++nt) {
                const bf16x8 bb = *(const bf16x8*)(sm.wb + (wv * 128 + nt * 16 + ln) * W2T_ST + ks * 32 + q * 8);
                acc[0][nt] = __builtin_amdgcn_mfma_f32_16x16x32_bf16(a0, bb, acc[0][nt], 0, 0, 0);
                acc[1][nt] = __builtin_amdgcn_mfma_f32_16x16x32_bf16(a1, bb, acc[1][nt], 0, 0, 0);
            }
        }
    }

    // ---- epilogue: out[token] += w * (acc + b2) ----
    float b2v[8];
#pragma unroll
    for (int nt = 0; nt < 8; ++nt) b2v[nt] = b2[(size_t)e * D + wv * 128 + nt * 16 + ln];
#pragma unroll
    for (int mt = 0; mt < 2; ++mt) {
#pragma unroll
        for (int r = 0; r < 4; ++r) {
            const int m = mt * 16 + q * 4 + r;
            if (tile * MT + m < (int)ncnt) {
                const int t = sm.toks[m];
                const float wgt = sm.wgts[m];
                float* orow = out + (size_t)t * D + wv * 128 + ln;
#pragma unroll
                for (int nt = 0; nt < 8; ++nt) {
                    atomicAdd(orow + nt * 16, wgt * (acc[mt][nt][r] + b2v[nt]));
                }
            }
        }
    }
}

// ---------------- launch ----------------
extern "C" void kernel_launch(void* const* d_in, const int* in_sizes, int n_in,
                              void* d_out, int out_size, void* d_ws, size_t ws_size,
                              hipStream_t stream) {
    const float* x  = (const float*)d_in[0];
    const float* rw = (const float*)d_in[1];
    const float* rb = (const float*)d_in[2];
    const float* w1 = (const float*)d_in[3];
    const float* b1 = (const float*)d_in[4];
    const float* w2 = (const float*)d_in[5];
    const float* b2 = (const float*)d_in[6];
    float* out = (float*)d_out;

    unsigned* cnt      = (unsigned*)d_ws;
    unsigned* tok_list = (unsigned*)((char*)d_ws + 1024);
    float*    w_list   = (float*)((char*)d_ws + 1024 + (size_t)E * B * 4);

    hipMemsetAsync(d_ws, 0, 1024, stream);                                // counters
    hipMemsetAsync(d_out, 0, (size_t)out_size * sizeof(float), stream);   // fp32 zeros

    router_kernel<<<B / 4, 256, 0, stream>>>(x, rw, rb, cnt, tok_list, w_list);

    ffn_kernel<<<dim3(B / MT, E), 256, 0, stream>>>(x, w1, b1, w2, b2, out,
                                                    cnt, tok_list, w_list);
}

// Round 2
// 1772.004 us; speedup vs baseline: 5.1898x; 5.1898x over previous
//
#include <hip/hip_runtime.h>
#include <hip/hip_bf16.h>

// ---------------- problem constants ----------------
constexpr int B = 65536;
constexpr int D = 512;
constexpr int E = 8;
constexpr int H = 2048;

typedef __bf16 bf16x8 __attribute__((ext_vector_type(8)));
typedef float  f32x4  __attribute__((ext_vector_type(4)));

__device__ __forceinline__ unsigned short f2bf(float f) {
    unsigned u = __float_as_uint(f);
    u += 0x7FFFu + ((u >> 16) & 1u);   // round-to-nearest-even
    return (unsigned short)(u >> 16);
}

// async global->LDS DMA, 16 B per lane, LDS dest = uniform base + lane*16
__device__ __forceinline__ void dma16(const void* g, void* lds) {
    auto* gp = reinterpret_cast<const __attribute__((address_space(1))) unsigned*>(
        reinterpret_cast<uintptr_t>(g));
    auto* lp = reinterpret_cast<__attribute__((address_space(3))) unsigned*>(
        reinterpret_cast<uintptr_t>(lds));
    __builtin_amdgcn_global_load_lds(gp, lp, 16, 0, 0);
}

// ---------------- kernel: router (thread per token) ----------------
__global__ __launch_bounds__(128) void router2(
    const float* __restrict__ x, const float* __restrict__ rw,
    const float* __restrict__ rb, unsigned* __restrict__ cnt,
    unsigned* __restrict__ tok_list, float* __restrict__ w_list) {
    __shared__ unsigned lcnt[E];
    __shared__ unsigned gbase[E];
    const int tid = threadIdx.x;
    if (tid < E) lcnt[tid] = 0u;
    __syncthreads();

    const int t = blockIdx.x * 128 + tid;
    const float4* xr = (const float4*)(x + (size_t)t * D);
    float acc[E];
#pragma unroll
    for (int e = 0; e < E; ++e) acc[e] = 0.f;

    for (int i = 0; i < D / 4; ++i) {
        const float4 xv = xr[i];
        const float* wr = rw + (size_t)i * 4 * E;   // wave-uniform -> s_load
        const float xs0 = xv.x, xs1 = xv.y, xs2 = xv.z, xs3 = xv.w;
#pragma unroll
        for (int e = 0; e < E; ++e) {
            acc[e] += xs0 * wr[e] + xs1 * wr[E + e] + xs2 * wr[2 * E + e]
                    + xs3 * wr[3 * E + e];
        }
    }
#pragma unroll
    for (int e = 0; e < E; ++e) acc[e] += rb[e];

    int e0 = 0; float l0 = acc[0];
#pragma unroll
    for (int e = 1; e < E; ++e) if (acc[e] > l0) { l0 = acc[e]; e0 = e; }
    int e1 = (e0 == 0) ? 1 : 0; float l1 = acc[e1];
#pragma unroll
    for (int e = 0; e < E; ++e)
        if (e != e0 && e != e1 && acc[e] > l1) { l1 = acc[e]; e1 = e; }
    // need lowest-index among ties / proper second max: redo scan cleanly
    e1 = -1; l1 = -3.4e38f;
#pragma unroll
    for (int e = 0; e < E; ++e)
        if (e != e0 && acc[e] > l1) { l1 = acc[e]; e1 = e; }

    const float w0 = 1.f / (1.f + expf(l1 - l0));   // renorm top-2 softmax
    const float w1v = 1.f - w0;

    const unsigned r0 = atomicAdd(&lcnt[e0], 1u);
    const unsigned r1 = atomicAdd(&lcnt[e1], 1u);
    __syncthreads();
    if (tid < E) gbase[tid] = atomicAdd(&cnt[tid], lcnt[tid]);
    __syncthreads();
    const unsigned s0 = gbase[e0] + r0;
    const unsigned s1 = gbase[e1] + r1;
    tok_list[(size_t)e0 * B + s0] = (unsigned)t;  w_list[(size_t)e0 * B + s0] = w0;
    tok_list[(size_t)e1 * B + s1] = (unsigned)t;  w_list[(size_t)e1 * B + s1] = w1v;
}

// ---------------- kernel: fp32 [R][C] -> bf16 [C][R] transpose (per expert z) ----
__global__ __launch_bounds__(256) void transpose_bf16(
    const float* __restrict__ in, unsigned short* __restrict__ outp,
    int R, int C) {
    __shared__ unsigned short T[64][72];
    const int e = blockIdx.z;
    const int c0 = blockIdx.x * 64, r0 = blockIdx.y * 64;
    const float* ine = in + (size_t)e * R * C;
    unsigned short* oute = outp + (size_t)e * R * C;
    const int tid = threadIdx.x;
    const int rl = tid >> 2, cl = (tid & 3) * 16;

    const float* src = ine + (size_t)(r0 + rl) * C + c0 + cl;
    unsigned pk[8];
#pragma unroll
    for (int i = 0; i < 4; ++i) {
        const float4 v = *(const float4*)(src + i * 4);
        pk[2 * i]     = (unsigned)f2bf(v.x) | ((unsigned)f2bf(v.y) << 16);
        pk[2 * i + 1] = (unsigned)f2bf(v.z) | ((unsigned)f2bf(v.w) << 16);
    }
    *(uint4*)(&T[rl][cl])     = make_uint4(pk[0], pk[1], pk[2], pk[3]);
    *(uint4*)(&T[rl][cl + 8]) = make_uint4(pk[4], pk[5], pk[6], pk[7]);
    __syncthreads();

    unsigned po[8];
#pragma unroll
    for (int j = 0; j < 8; ++j) {
        po[j] = (unsigned)T[cl + 2 * j][rl] | ((unsigned)T[cl + 2 * j + 1][rl] << 16);
    }
    unsigned short* dst = oute + (size_t)(c0 + rl) * R + r0 + cl;
    *(uint4*)(dst)     = make_uint4(po[0], po[1], po[2], po[3]);
    *(uint4*)(dst + 8) = make_uint4(po[4], po[5], po[6], po[7]);
}

// ---------------- kernel: gather+convert x rows for expert e -> xg bf16 ----
__global__ __launch_bounds__(256) void pregather(
    const float* __restrict__ x, const unsigned* __restrict__ cnt,
    const unsigned* __restrict__ tok_list, unsigned short* __restrict__ xg,
    int e) {
    const int w = threadIdx.x >> 6, lane = threadIdx.x & 63;
    const int slot = blockIdx.x * 4 + w;
    if ((unsigned)slot >= cnt[e]) return;
    const unsigned tok = tok_list[(size_t)e * B + slot];
    const float* src = x + (size_t)tok * D + lane * 8;
    const float4 v0 = *(const float4*)(src);
    const float4 v1 = *(const float4*)(src + 4);
    unsigned p0 = (unsigned)f2bf(v0.x) | ((unsigned)f2bf(v0.y) << 16);
    unsigned p1 = (unsigned)f2bf(v0.z) | ((unsigned)f2bf(v0.w) << 16);
    unsigned p2 = (unsigned)f2bf(v1.x) | ((unsigned)f2bf(v1.y) << 16);
    unsigned p3 = (unsigned)f2bf(v1.z) | ((unsigned)f2bf(v1.w) << 16);
    *(uint4*)(xg + (size_t)slot * D + lane * 8) = make_uint4(p0, p1, p2, p3);
}

// ---------------- kernel: GEMM1  h = relu(xg @ w1s^T + b1) ----------------
// m97 structure: 128x128 tile, BK=32, DMA staging, 4 waves of 64x64.
__global__ __launch_bounds__(256) void gemm1(
    const unsigned short* __restrict__ xg, const unsigned short* __restrict__ w1s,
    const float* __restrict__ b1, unsigned short* __restrict__ hbuf,
    const unsigned* __restrict__ cnt, int e) {
    __shared__ unsigned short At[128 * 32];
    __shared__ unsigned short Bt[128 * 32];
    const unsigned ncnt = cnt[e];
    const int m0 = blockIdx.x * 128;
    if ((unsigned)m0 >= ncnt) return;
    const int n0 = blockIdx.y * 128;

    const int tid = threadIdx.x, wv = tid >> 6, lane = tid & 63;
    const int ln = lane & 15, q = lane >> 4;
    const int wm = wv & 1, wn = wv >> 1;
    const int r4 = lane >> 2, pc = lane & 3;
    const unsigned short* w1e = w1s + (size_t)e * H * D;

    f32x4 acc[4][4];
#pragma unroll
    for (int i = 0; i < 4; ++i)
#pragma unroll
        for (int j = 0; j < 4; ++j) acc[i][j] = (f32x4){0.f, 0.f, 0.f, 0.f};

    for (int k0 = 0; k0 < D; k0 += 32) {
#pragma unroll
        for (int j = 0; j < 2; ++j) {
            const int ii = wv * 2 + j;
            dma16(xg  + (size_t)(m0 + ii * 16 + r4) * D + k0 + pc * 8, At + ii * 512);
            dma16(w1e + (size_t)(n0 + ii * 16 + r4) * D + k0 + pc * 8, Bt + ii * 512);
        }
        __syncthreads();
        bf16x8 af[4], bfr[4];
#pragma unroll
        for (int i = 0; i < 4; ++i) {
            af[i]  = *(const bf16x8*)(At + (wm * 64 + i * 16 + ln) * 32 + q * 8);
            bfr[i] = *(const bf16x8*)(Bt + (wn * 64 + i * 16 + ln) * 32 + q * 8);
        }
#pragma unroll
        for (int mt = 0; mt < 4; ++mt)
#pragma unroll
            for (int nt = 0; nt < 4; ++nt)
                acc[mt][nt] = __builtin_amdgcn_mfma_f32_16x16x32_bf16(
                    af[mt], bfr[nt], acc[mt][nt], 0, 0, 0);
        __syncthreads();
    }

#pragma unroll
    for (int nt = 0; nt < 4; ++nt) {
        const int n = n0 + wn * 64 + nt * 16 + ln;
        const float b1v = b1[(size_t)e * H + n];
#pragma unroll
        for (int mt = 0; mt < 4; ++mt) {
#pragma unroll
            for (int r = 0; r < 4; ++r) {
                const int slot = m0 + wm * 64 + mt * 16 + q * 4 + r;
                if ((unsigned)slot < ncnt) {
                    float v = acc[mt][nt][r] + b1v;
                    v = v > 0.f ? v : 0.f;
                    hbuf[(size_t)slot * H + n] = f2bf(v);
                }
            }
        }
    }
}

// ---------------- kernel: GEMM2  out[tok] += wgt*(h @ w2s^T + b2) ----------------
__global__ __launch_bounds__(256) void gemm2(
    const unsigned short* __restrict__ hbuf, const unsigned short* __restrict__ w2s,
    const float* __restrict__ b2, const unsigned* __restrict__ cnt,
    const unsigned* __restrict__ tok_list, const float* __restrict__ w_list,
    float* __restrict__ out, int e) {
    __shared__ unsigned short At[128 * 32];
    __shared__ unsigned short Bt[128 * 32];
    const unsigned ncnt = cnt[e];
    const int m0 = blockIdx.x * 128;
    if ((unsigned)m0 >= ncnt) return;
    const int n0 = blockIdx.y * 128;

    const int tid = threadIdx.x, wv = tid >> 6, lane = tid & 63;
    const int ln = lane & 15, q = lane >> 4;
    const int wm = wv & 1, wn = wv >> 1;
    const int r4 = lane >> 2, pc = lane & 3;
    const unsigned short* w2e = w2s + (size_t)e * D * H;

    f32x4 acc[4][4];
#pragma unroll
    for (int i = 0; i < 4; ++i)
#pragma unroll
        for (int j = 0; j < 4; ++j) acc[i][j] = (f32x4){0.f, 0.f, 0.f, 0.f};

    for (int k0 = 0; k0 < H; k0 += 32) {
#pragma unroll
        for (int j = 0; j < 2; ++j) {
            const int ii = wv * 2 + j;
            dma16(hbuf + (size_t)(m0 + ii * 16 + r4) * H + k0 + pc * 8, At + ii * 512);
            dma16(w2e  + (size_t)(n0 + ii * 16 + r4) * H + k0 + pc * 8, Bt + ii * 512);
        }
        __syncthreads();
        bf16x8 af[4], bfr[4];
#pragma unroll
        for (int i = 0; i < 4; ++i) {
            af[i]  = *(const bf16x8*)(At + (wm * 64 + i * 16 + ln) * 32 + q * 8);
            bfr[i] = *(const bf16x8*)(Bt + (wn * 64 + i * 16 + ln) * 32 + q * 8);
        }
#pragma unroll
        for (int mt = 0; mt < 4; ++mt)
#pragma unroll
            for (int nt = 0; nt < 4; ++nt)
                acc[mt][nt] = __builtin_amdgcn_mfma_f32_16x16x32_bf16(
                    af[mt], bfr[nt], acc[mt][nt], 0, 0, 0);
        __syncthreads();
    }

    float b2v[4];
#pragma unroll
    for (int nt = 0; nt < 4; ++nt)
        b2v[nt] = b2[(size_t)e * D + n0 + wn * 64 + nt * 16 + ln];

#pragma unroll
    for (int mt = 0; mt < 4; ++mt) {
#pragma unroll
        for (int r = 0; r < 4; ++r) {
            const int slot = m0 + wm * 64 + mt * 16 + q * 4 + r;
            if ((unsigned)slot < ncnt) {
                const unsigned tok = tok_list[(size_t)e * B + slot];
                const float wgt = w_list[(size_t)e * B + slot];
                float* orow = out + (size_t)tok * D + n0 + wn * 64;
#pragma unroll
                for (int nt = 0; nt < 4; ++nt) {
                    const int c = nt * 16 + ln;
                    orow[c] += wgt * (acc[mt][nt][r] + b2v[nt]);  // no race: 1 visit per token per launch
                }
            }
        }
    }
}

// ============ fallback (round-1 fused kernel) if ws_size is small ============
constexpr int MT = 32;
constexpr int HC = 64;
constexpr int XS_ST  = D + 8;
constexpr int W1T_ST = D + 8;
constexpr int W2T_ST = HC + 8;
constexpr int HT_ST  = HC + 8;

struct alignas(16) Smem {
    unsigned short xs[MT * XS_ST];
    unsigned short wb[36864];
    unsigned short ht[MT * HT_ST];
    int   toks[MT];
    float wgts[MT];
};

__global__ __launch_bounds__(256) void ffn_kernel(
    const float* __restrict__ x,
    const float* __restrict__ w1, const float* __restrict__ b1,
    const float* __restrict__ w2, const float* __restrict__ b2,
    float* __restrict__ out,
    const unsigned* __restrict__ cnt,
    const unsigned* __restrict__ tok_list, const float* __restrict__ w_list) {
    __shared__ Smem sm;
    const int tile = blockIdx.x;
    const int e = blockIdx.y;
    const unsigned ncnt = cnt[e];
    if ((unsigned)(tile * MT) >= ncnt) return;
    const int tid = threadIdx.x;
    const int wv = tid >> 6;
    const int lane = tid & 63;
    const int ln = lane & 15;
    const int q = lane >> 4;
    if (tid < MT) {
        const int li = tile * MT + tid;
        if (li < (int)ncnt) {
            sm.toks[tid] = (int)tok_list[(size_t)e * B + li];
            sm.wgts[tid] = w_list[(size_t)e * B + li];
        } else {
            sm.toks[tid] = (int)tok_list[(size_t)e * B + tile * MT];
            sm.wgts[tid] = 0.f;
        }
    }
    {
        const int r = tid >> 3;
        const int c8 = tid & 7;
        const int li = tile * MT + r;
        const unsigned tok = (li < (int)ncnt) ? tok_list[(size_t)e * B + li]
                                              : tok_list[(size_t)e * B + tile * MT];
        const float* src = x + (size_t)tok * D;
#pragma unroll
        for (int i = 0; i < 16; ++i) {
            const int d = (c8 + 8 * i) * 4;
            const float4 v = *(const float4*)(src + d);
            uint2 pk;
            pk.x = (unsigned)f2bf(v.x) | ((unsigned)f2bf(v.y) << 16);
            pk.y = (unsigned)f2bf(v.z) | ((unsigned)f2bf(v.w) << 16);
            *(uint2*)(sm.xs + r * XS_ST + d) = pk;
        }
    }
    f32x4 acc[2][8];
#pragma unroll
    for (int mt = 0; mt < 2; ++mt)
#pragma unroll
        for (int nt = 0; nt < 8; ++nt) acc[mt][nt] = (f32x4){0.f, 0.f, 0.f, 0.f};
    for (int hc = 0; hc < H; hc += HC) {
        __syncthreads();
        {
            const int nf = tid & 15;
            const int d0 = tid >> 4;
            const float* src = w1 + (size_t)e * D * H + hc + nf * 4;
#pragma unroll 4
            for (int i = 0; i < 32; ++i) {
                const int d = d0 + 16 * i;
                const float4 v = *(const float4*)(src + (size_t)d * H);
                sm.wb[(nf * 4 + 0) * W1T_ST + d] = f2bf(v.x);
                sm.wb[(nf * 4 + 1) * W1T_ST + d] = f2bf(v.y);
                sm.wb[(nf * 4 + 2) * W1T_ST + d] = f2bf(v.z);
                sm.wb[(nf * 4 + 3) * W1T_ST + d] = f2bf(v.w);
            }
        }
        __syncthreads();
        {
            f32x4 c0 = (f32x4){0.f, 0.f, 0.f, 0.f};
            f32x4 c1 = (f32x4){0.f, 0.f, 0.f, 0.f};
#pragma unroll
            for (int ks = 0; ks < D / 32; ++ks) {
                const bf16x8 a0 = *(const bf16x8*)(sm.xs + ln * XS_ST + ks * 32 + q * 8);
                const bf16x8 a1 = *(const bf16x8*)(sm.xs + (16 + ln) * XS_ST + ks * 32 + q * 8);
                const bf16x8 bb = *(const bf16x8*)(sm.wb + (wv * 16 + ln) * W1T_ST + ks * 32 + q * 8);
                c0 = __builtin_amdgcn_mfma_f32_16x16x32_bf16(a0, bb, c0, 0, 0, 0);
                c1 = __builtin_amdgcn_mfma_f32_16x16x32_bf16(a1, bb, c1, 0, 0, 0);
            }
            const float b1v = b1[(size_t)e * H + hc + wv * 16 + ln];
#pragma unroll
            for (int r = 0; r < 4; ++r) {
                float h0 = c0[r] + b1v; h0 = h0 > 0.f ? h0 : 0.f;
                float h1 = c1[r] + b1v; h1 = h1 > 0.f ? h1 : 0.f;
                sm.ht[(q * 4 + r) * HT_ST + wv * 16 + ln] = f2bf(h0);
                sm.ht[(16 + q * 4 + r) * HT_ST + wv * 16 + ln] = f2bf(h1);
            }
        }
        __syncthreads();
        {
#pragma unroll 4
            for (int i = 0; i < 32; ++i) {
                const int idx = tid + 256 * i;
                const int k = idx >> 7;
                const int d4 = idx & 127;
                const float4 v = *(const float4*)(w2 + ((size_t)(e * H + hc + k)) * D + d4 * 4);
                sm.wb[(d4 * 4 + 0) * W2T_ST + k] = f2bf(v.x);
                sm.wb[(d4 * 4 + 1) * W2T_ST + k] = f2bf(v.y);
                sm.wb[(d4 * 4 + 2) * W2T_ST + k] = f2bf(v.z);
                sm.wb[(d4 * 4 + 3) * W2T_ST + k] = f2bf(v.w);
            }
        }
        __syncthreads();
#pragma unroll
        for (int ks = 0; ks < HC / 32; ++ks) {
            const bf16x8 a0 = *(const bf16x8*)(sm.ht + ln * HT_ST + ks * 32 + q * 8);
            const bf16x8 a1 = *(const bf16x8*)(sm.ht + (16 + ln) * HT_ST + ks * 32 + q * 8);
#pragma unroll
            for (int nt = 0; nt < 8; ++nt) {
                const bf16x8 bb = *(const bf16x8*)(sm.wb + (wv * 128 + nt * 16 + ln) * W2T_ST + ks * 32 + q * 8);
                acc[0][nt] = __builtin_amdgcn_mfma_f32_16x16x32_bf16(a0, bb, acc[0][nt], 0, 0, 0);
                acc[1][nt] = __builtin_amdgcn_mfma_f32_16x16x32_bf16(a1, bb, acc[1][nt], 0, 0, 0);
            }
        }
    }
    float b2v[8];
#pragma unroll
    for (int nt = 0; nt < 8; ++nt) b2v[nt] = b2[(size_t)e * D + wv * 128 + nt * 16 + ln];
#pragma unroll
    for (int mt = 0; mt < 2; ++mt) {
#pragma unroll
        for (int r = 0; r < 4; ++r) {
            const int m = mt * 16 + q * 4 + r;
            if (tile * MT + m < (int)ncnt) {
                const int t = sm.toks[m];
                const float wgt = sm.wgts[m];
                float* orow = out + (size_t)t * D + wv * 128 + ln;
#pragma unroll
                for (int nt = 0; nt < 8; ++nt) {
                    atomicAdd(orow + nt * 16, wgt * (acc[mt][nt][r] + b2v[nt]));
                }
            }
        }
    }
}

// ---------------- launch ----------------
extern "C" void kernel_launch(void* const* d_in, const int* in_sizes, int n_in,
                              void* d_out, int out_size, void* d_ws, size_t ws_size,
                              hipStream_t stream) {
    const float* x  = (const float*)d_in[0];
    const float* rw = (const float*)d_in[1];
    const float* rb = (const float*)d_in[2];
    const float* w1 = (const float*)d_in[3];
    const float* b1 = (const float*)d_in[4];
    const float* w2 = (const float*)d_in[5];
    const float* b2 = (const float*)d_in[6];
    float* out = (float*)d_out;

    char* ws = (char*)d_ws;
    const size_t off_tok = 1024;
    const size_t off_wl  = off_tok + (size_t)E * B * 4;
    const size_t off_w1s = off_wl  + (size_t)E * B * 4;
    const size_t off_w2s = off_w1s + (size_t)E * D * H * 2;
    const size_t off_xg  = off_w2s + (size_t)E * D * H * 2;

    unsigned* cnt      = (unsigned*)ws;
    unsigned* tok_list = (unsigned*)(ws + off_tok);
    float*    w_list   = (float*)(ws + off_wl);

    // per-expert slot capacity from remaining workspace (host-side, deterministic)
    long long avail = (long long)ws_size - (long long)off_xg;
    int cap = 0;
    if (avail > 0) {
        cap = (int)(avail / ((size_t)D * 2 + (size_t)H * 2));
        cap &= ~127;
        if (cap > 32768) cap = 32768;
    }

    hipMemsetAsync(ws, 0, 1024, stream);                                  // counters
    hipMemsetAsync(d_out, 0, (size_t)out_size * sizeof(float), stream);   // fp32 zeros

    router2<<<B / 128, 128, 0, stream>>>(x, rw, rb, cnt, tok_list, w_list);

    if (cap >= 20480) {
        unsigned short* w1s  = (unsigned short*)(ws + off_w1s);
        unsigned short* w2s  = (unsigned short*)(ws + off_w2s);
        unsigned short* xg   = (unsigned short*)(ws + off_xg);
        unsigned short* hbuf = xg + (size_t)cap * D;

        // w1 [E][D][H] -> w1s [E][H][D]; w2 [E][H][D] -> w2s [E][D][H]
        transpose_bf16<<<dim3(H / 64, D / 64, E), 256, 0, stream>>>(w1, w1s, D, H);
        transpose_bf16<<<dim3(D / 64, H / 64, E), 256, 0, stream>>>(w2, w2s, H, D);

        for (int e = 0; e < E; ++e) {
            pregather<<<cap / 4, 256, 0, stream>>>(x, cnt, tok_list, xg, e);
            gemm1<<<dim3(cap / 128, H / 128), 256, 0, stream>>>(xg, w1s, b1, hbuf, cnt, e);
            gemm2<<<dim3(cap / 128, D / 128), 256, 0, stream>>>(hbuf, w2s, b2, cnt,
                                                                tok_list, w_list, out, e);
        }
    } else {
        ffn_kernel<<<dim3(B / MT, E), 256, 0, stream>>>(x, w1, b1, w2, b2, out,
                                                        cnt, tok_list, w_list);
    }
}

// Round 3
// 1717.210 us; speedup vs baseline: 5.3554x; 1.0319x over previous
//
#include <hip/hip_runtime.h>
#include <hip/hip_bf16.h>

// ---------------- problem constants ----------------
constexpr int B = 65536;
constexpr int D = 512;
constexpr int E = 8;
constexpr int H = 2048;
constexpr int CT_ST = 140;   // epilogue LDS C-tile row stride (shorts); 2-way banks max

typedef __bf16 bf16x8 __attribute__((ext_vector_type(8)));
typedef float  f32x4  __attribute__((ext_vector_type(4)));

__device__ __forceinline__ unsigned short f2bf(float f) {
    unsigned u = __float_as_uint(f);
    u += 0x7FFFu + ((u >> 16) & 1u);   // round-to-nearest-even
    return (unsigned short)(u >> 16);
}

// async global->LDS DMA, 16 B per lane; global addr may be per-lane (gather OK),
// LDS dest = wave-uniform base + lane*16
__device__ __forceinline__ void dma16(const void* g, void* lds) {
    auto* gp = reinterpret_cast<const __attribute__((address_space(1))) unsigned*>(
        reinterpret_cast<uintptr_t>(g));
    auto* lp = reinterpret_cast<__attribute__((address_space(3))) unsigned*>(
        reinterpret_cast<uintptr_t>(lds));
    __builtin_amdgcn_global_load_lds(gp, lp, 16, 0, 0);
}

// ---------------- kernel: bulk x fp32 -> bf16 ----------------
__global__ __launch_bounds__(256) void convert_x(
    const float* __restrict__ x, unsigned short* __restrict__ xb) {
    const size_t i = ((size_t)blockIdx.x * 256 + threadIdx.x) * 8;
    const float4 v0 = *(const float4*)(x + i);
    const float4 v1 = *(const float4*)(x + i + 4);
    uint4 p;
    p.x = (unsigned)f2bf(v0.x) | ((unsigned)f2bf(v0.y) << 16);
    p.y = (unsigned)f2bf(v0.z) | ((unsigned)f2bf(v0.w) << 16);
    p.z = (unsigned)f2bf(v1.x) | ((unsigned)f2bf(v1.y) << 16);
    p.w = (unsigned)f2bf(v1.z) | ((unsigned)f2bf(v1.w) << 16);
    *(uint4*)(xb + i) = p;
}

// ---------------- kernel: router (thread per token) ----------------
__global__ __launch_bounds__(128) void router2(
    const float* __restrict__ x, const float* __restrict__ rw,
    const float* __restrict__ rb, unsigned* __restrict__ cnt,
    unsigned* __restrict__ tok_list, float* __restrict__ w_list) {
    __shared__ unsigned lcnt[E];
    __shared__ unsigned gbase[E];
    const int tid = threadIdx.x;
    if (tid < E) lcnt[tid] = 0u;
    __syncthreads();

    const int t = blockIdx.x * 128 + tid;
    const float4* xr = (const float4*)(x + (size_t)t * D);
    float acc[E];
#pragma unroll
    for (int e = 0; e < E; ++e) acc[e] = 0.f;

    for (int i = 0; i < D / 4; ++i) {
        const float4 xv = xr[i];
        const float* wr = rw + (size_t)i * 4 * E;   // wave-uniform -> s_load
#pragma unroll
        for (int e = 0; e < E; ++e) {
            acc[e] += xv.x * wr[e] + xv.y * wr[E + e] + xv.z * wr[2 * E + e]
                    + xv.w * wr[3 * E + e];
        }
    }
#pragma unroll
    for (int e = 0; e < E; ++e) acc[e] += rb[e];

    int e0 = 0; float l0 = acc[0];
#pragma unroll
    for (int e = 1; e < E; ++e) if (acc[e] > l0) { l0 = acc[e]; e0 = e; }
    int e1 = -1; float l1 = -3.4e38f;
#pragma unroll
    for (int e = 0; e < E; ++e)
        if (e != e0 && acc[e] > l1) { l1 = acc[e]; e1 = e; }

    const float w0 = 1.f / (1.f + expf(l1 - l0));   // renorm top-2 softmax
    const float w1v = 1.f - w0;

    const unsigned r0 = atomicAdd(&lcnt[e0], 1u);
    const unsigned r1 = atomicAdd(&lcnt[e1], 1u);
    __syncthreads();
    if (tid < E) gbase[tid] = atomicAdd(&cnt[tid], lcnt[tid]);
    __syncthreads();
    const unsigned s0 = gbase[e0] + r0;
    const unsigned s1 = gbase[e1] + r1;
    tok_list[(size_t)e0 * B + s0] = (unsigned)t;  w_list[(size_t)e0 * B + s0] = w0;
    tok_list[(size_t)e1 * B + s1] = (unsigned)t;  w_list[(size_t)e1 * B + s1] = w1v;
}

// ---------------- kernel: pad per-expert lists to multiple of 128 ----------------
__global__ __launch_bounds__(128) void pad_counts(
    const unsigned* __restrict__ cnt, unsigned* __restrict__ cntp,
    unsigned* __restrict__ tok_list, float* __restrict__ w_list, int cap) {
    const int tid = threadIdx.x;
    for (int e = 0; e < E; ++e) {
        const unsigned c = cnt[e];
        unsigned p = (c + 127u) & ~127u;
        if (p > (unsigned)cap) p = (unsigned)cap;
        if (c + tid < p) {
            tok_list[(size_t)e * B + c + tid] = 0u;   // valid token, weight 0
            w_list[(size_t)e * B + c + tid] = 0.f;
        }
        if (tid == 0) cntp[e] = p;
    }
}

// ---------------- kernel: fp32 [R][C] -> bf16 [C][R] transpose (per expert z) ----
__global__ __launch_bounds__(256) void transpose_bf16(
    const float* __restrict__ in, unsigned short* __restrict__ outp,
    int R, int C) {
    __shared__ unsigned short T[64][72];
    const int e = blockIdx.z;
    const int c0 = blockIdx.x * 64, r0 = blockIdx.y * 64;
    const float* ine = in + (size_t)e * R * C;
    unsigned short* oute = outp + (size_t)e * R * C;
    const int tid = threadIdx.x;
    const int rl = tid >> 2, cl = (tid & 3) * 16;

    const float* src = ine + (size_t)(r0 + rl) * C + c0 + cl;
    unsigned pk[8];
#pragma unroll
    for (int i = 0; i < 4; ++i) {
        const float4 v = *(const float4*)(src + i * 4);
        pk[2 * i]     = (unsigned)f2bf(v.x) | ((unsigned)f2bf(v.y) << 16);
        pk[2 * i + 1] = (unsigned)f2bf(v.z) | ((unsigned)f2bf(v.w) << 16);
    }
    *(uint4*)(&T[rl][cl])     = make_uint4(pk[0], pk[1], pk[2], pk[3]);
    *(uint4*)(&T[rl][cl + 8]) = make_uint4(pk[4], pk[5], pk[6], pk[7]);
    __syncthreads();

    unsigned po[8];
#pragma unroll
    for (int j = 0; j < 8; ++j) {
        po[j] = (unsigned)T[cl + 2 * j][rl] | ((unsigned)T[cl + 2 * j + 1][rl] << 16);
    }
    unsigned short* dst = oute + (size_t)(c0 + rl) * R + r0 + cl;
    *(uint4*)(dst)     = make_uint4(po[0], po[1], po[2], po[3]);
    *(uint4*)(dst + 8) = make_uint4(po[4], po[5], po[6], po[7]);
}

// ---------------- shared-memory layouts for the stage kernel ----------------
struct alignas(16) G1 {
    unsigned short At[128 * 32];        // 8 KB
    unsigned short Bt[128 * 32];        // 8 KB
    unsigned short Ct[64 * CT_ST];      // 17.5 KB epilogue staging
};
struct alignas(16) G2 {
    unsigned short At[128 * 32];
    unsigned short Bt[128 * 32];
    int   toks[128];
    float wgts[128];
};
union SmemU { G1 g1; G2 g2; };

// ---------------- kernel: pipeline stage ----------------
// blockIdx.y <  16 : gemm1 for expert e_w : hb_w[slot][H] = relu(xb[tok] @ w1s^T + b1)
// blockIdx.y >= 16 : gemm2 for expert e_r : out[tok] += wgt * (hb_r[slot] @ w2s^T + b2)
__global__ __launch_bounds__(256) void stage_kernel(
    const unsigned short* __restrict__ xb,
    const unsigned short* __restrict__ w1s, const unsigned short* __restrict__ w2s,
    const float* __restrict__ b1, const float* __restrict__ b2,
    const unsigned* __restrict__ cntp,
    const unsigned* __restrict__ tok_list, const float* __restrict__ w_list,
    unsigned short* __restrict__ hb_w, const unsigned short* __restrict__ hb_r,
    float* __restrict__ out, int e_w, int e_r) {
    __shared__ SmemU sm;
    const int tid = threadIdx.x, wv = tid >> 6, lane = tid & 63;
    const int ln = lane & 15, q = lane >> 4;
    const int wm = wv & 1, wn = wv >> 1;
    const int r4 = lane >> 2, pc = lane & 3;
    const int m0 = blockIdx.x * 128;

    f32x4 acc[4][4];
#pragma unroll
    for (int i = 0; i < 4; ++i)
#pragma unroll
        for (int j = 0; j < 4; ++j) acc[i][j] = (f32x4){0.f, 0.f, 0.f, 0.f};

    if (blockIdx.y < 16) {
        // ---------------- gemm1 ----------------
        if (e_w < 0) return;
        const int e = e_w;
        if ((unsigned)m0 >= cntp[e]) return;
        const int n0 = blockIdx.y * 128;
        const size_t base = (size_t)e * B;

        const unsigned ta0 = tok_list[base + m0 + (wv * 2 + 0) * 16 + r4];
        const unsigned ta1 = tok_list[base + m0 + (wv * 2 + 1) * 16 + r4];
        const unsigned short* ap0 = xb + (size_t)ta0 * D + pc * 8;
        const unsigned short* ap1 = xb + (size_t)ta1 * D + pc * 8;
        const unsigned short* w1e = w1s + (size_t)e * H * D;
        const unsigned short* bp0 = w1e + (size_t)(n0 + (wv * 2 + 0) * 16 + r4) * D + pc * 8;
        const unsigned short* bp1 = w1e + (size_t)(n0 + (wv * 2 + 1) * 16 + r4) * D + pc * 8;

        for (int k0 = 0; k0 < D; k0 += 32) {
            dma16(ap0 + k0, sm.g1.At + (wv * 2 + 0) * 512);
            dma16(ap1 + k0, sm.g1.At + (wv * 2 + 1) * 512);
            dma16(bp0 + k0, sm.g1.Bt + (wv * 2 + 0) * 512);
            dma16(bp1 + k0, sm.g1.Bt + (wv * 2 + 1) * 512);
            __syncthreads();
            bf16x8 af[4], bfr[4];
#pragma unroll
            for (int i = 0; i < 4; ++i) {
                af[i]  = *(const bf16x8*)(sm.g1.At + (wm * 64 + i * 16 + ln) * 32 + q * 8);
                bfr[i] = *(const bf16x8*)(sm.g1.Bt + (wn * 64 + i * 16 + ln) * 32 + q * 8);
            }
#pragma unroll
            for (int mt = 0; mt < 4; ++mt)
#pragma unroll
                for (int nt = 0; nt < 4; ++nt)
                    acc[mt][nt] = __builtin_amdgcn_mfma_f32_16x16x32_bf16(
                        af[mt], bfr[nt], acc[mt][nt], 0, 0, 0);
            __syncthreads();
        }

        // epilogue: bias+relu, stage 64-row chunks in LDS, coalesced 16B stores
        float b1v[4];
#pragma unroll
        for (int nt = 0; nt < 4; ++nt)
            b1v[nt] = b1[(size_t)e * H + n0 + wn * 64 + nt * 16 + ln];

#pragma unroll
        for (int c = 0; c < 2; ++c) {
            if (wm == c) {
#pragma unroll
                for (int mt = 0; mt < 4; ++mt)
#pragma unroll
                    for (int nt = 0; nt < 4; ++nt)
#pragma unroll
                        for (int r = 0; r < 4; ++r) {
                            const int lr = mt * 16 + q * 4 + r;
                            float v = acc[mt][nt][r] + b1v[nt];
                            v = v > 0.f ? v : 0.f;
                            sm.g1.Ct[lr * CT_ST + wn * 64 + nt * 16 + ln] = f2bf(v);
                        }
            }
            __syncthreads();
            {
                const int lr = tid >> 2, seg = tid & 3;
                const unsigned short* csrc = sm.g1.Ct + lr * CT_ST + seg * 32;
                unsigned short* gdst = hb_w + (size_t)(m0 + c * 64 + lr) * H + n0 + seg * 32;
#pragma unroll
                for (int u = 0; u < 4; ++u)
                    *(uint4*)(gdst + u * 8) = *(const uint4*)(csrc + u * 8);
            }
            __syncthreads();
        }
    } else {
        // ---------------- gemm2 ----------------
        if (e_r < 0) return;
        const int e = e_r;
        if ((unsigned)m0 >= cntp[e]) return;
        const int n0 = (blockIdx.y - 16) * 128;
        const size_t base = (size_t)e * B;

        if (tid < 128) {
            sm.g2.toks[tid] = (int)tok_list[base + m0 + tid];
            sm.g2.wgts[tid] = w_list[base + m0 + tid];
        }
        const unsigned short* ap0 = hb_r + (size_t)(m0 + (wv * 2 + 0) * 16 + r4) * H + pc * 8;
        const unsigned short* ap1 = hb_r + (size_t)(m0 + (wv * 2 + 1) * 16 + r4) * H + pc * 8;
        const unsigned short* w2e = w2s + (size_t)e * D * H;
        const unsigned short* bp0 = w2e + (size_t)(n0 + (wv * 2 + 0) * 16 + r4) * H + pc * 8;
        const unsigned short* bp1 = w2e + (size_t)(n0 + (wv * 2 + 1) * 16 + r4) * H + pc * 8;

        for (int k0 = 0; k0 < H; k0 += 32) {
            dma16(ap0 + k0, sm.g2.At + (wv * 2 + 0) * 512);
            dma16(ap1 + k0, sm.g2.At + (wv * 2 + 1) * 512);
            dma16(bp0 + k0, sm.g2.Bt + (wv * 2 + 0) * 512);
            dma16(bp1 + k0, sm.g2.Bt + (wv * 2 + 1) * 512);
            __syncthreads();
            bf16x8 af[4], bfr[4];
#pragma unroll
            for (int i = 0; i < 4; ++i) {
                af[i]  = *(const bf16x8*)(sm.g2.At + (wm * 64 + i * 16 + ln) * 32 + q * 8);
                bfr[i] = *(const bf16x8*)(sm.g2.Bt + (wn * 64 + i * 16 + ln) * 32 + q * 8);
            }
#pragma unroll
            for (int mt = 0; mt < 4; ++mt)
#pragma unroll
                for (int nt = 0; nt < 4; ++nt)
                    acc[mt][nt] = __builtin_amdgcn_mfma_f32_16x16x32_bf16(
                        af[mt], bfr[nt], acc[mt][nt], 0, 0, 0);
            __syncthreads();
        }

        float b2v[4];
#pragma unroll
        for (int nt = 0; nt < 4; ++nt)
            b2v[nt] = b2[(size_t)e * D + n0 + wn * 64 + nt * 16 + ln];

#pragma unroll
        for (int mt = 0; mt < 4; ++mt) {
#pragma unroll
            for (int r = 0; r < 4; ++r) {
                const int m = wm * 64 + mt * 16 + q * 4 + r;
                const float wgt = sm.g2.wgts[m];
                if (wgt != 0.f) {                 // skip pad rows (avoids token-0 RMW race)
                    const int tok = sm.g2.toks[m];
                    float* orow = out + (size_t)tok * D + n0 + wn * 64 + ln;
#pragma unroll
                    for (int nt = 0; nt < 4; ++nt)
                        orow[nt * 16] += wgt * (acc[mt][nt][r] + b2v[nt]);
                }
            }
        }
    }
}

// ---------------- launch ----------------
extern "C" void kernel_launch(void* const* d_in, const int* in_sizes, int n_in,
                              void* d_out, int out_size, void* d_ws, size_t ws_size,
                              hipStream_t stream) {
    const float* x  = (const float*)d_in[0];
    const float* rw = (const float*)d_in[1];
    const float* rb = (const float*)d_in[2];
    const float* w1 = (const float*)d_in[3];
    const float* b1 = (const float*)d_in[4];
    const float* w2 = (const float*)d_in[5];
    const float* b2 = (const float*)d_in[6];
    float* out = (float*)d_out;

    char* ws = (char*)d_ws;
    const size_t off_tok = 1024;
    const size_t off_wl  = off_tok + (size_t)E * B * 4;
    const size_t off_w1s = off_wl  + (size_t)E * B * 4;
    const size_t off_w2s = off_w1s + (size_t)E * D * H * 2;
    const size_t off_xb  = off_w2s + (size_t)E * D * H * 2;
    const size_t off_hb  = off_xb  + (size_t)B * D * 2;

    unsigned* cnt      = (unsigned*)ws;
    unsigned* cntp     = (unsigned*)(ws + 256);
    unsigned* tok_list = (unsigned*)(ws + off_tok);
    float*    w_list   = (float*)(ws + off_wl);
    unsigned short* w1s = (unsigned short*)(ws + off_w1s);
    unsigned short* w2s = (unsigned short*)(ws + off_w2s);
    unsigned short* xb  = (unsigned short*)(ws + off_xb);

    // workspace-driven config (deterministic per call -> graph-safe)
    const size_t rem = (ws_size > off_hb) ? (ws_size - off_hb) : 0;
    const size_t hrow = (size_t)H * 2;
    int cap; bool pipelined;
    {
        size_t cp = (rem / 2 / hrow) & ~(size_t)127;
        if (cp > 24576) cp = 24576;
        if (cp >= 20480) { pipelined = true; cap = (int)cp; }
        else {
            pipelined = false;
            size_t cs = (rem / hrow) & ~(size_t)127;
            if (cs > 24576) cs = 24576;
            cap = (int)cs;
        }
    }
    unsigned short* hb0 = (unsigned short*)(ws + off_hb);
    unsigned short* hb1 = pipelined ? hb0 + (size_t)cap * H : hb0;

    hipMemsetAsync(ws, 0, 1024, stream);                                  // counters
    hipMemsetAsync(d_out, 0, (size_t)out_size * sizeof(float), stream);   // fp32 zeros

    convert_x<<<(B * D) / 2048, 256, 0, stream>>>(x, xb);
    transpose_bf16<<<dim3(H / 64, D / 64, E), 256, 0, stream>>>(w1, w1s, D, H);
    transpose_bf16<<<dim3(D / 64, H / 64, E), 256, 0, stream>>>(w2, w2s, H, D);
    router2<<<B / 128, 128, 0, stream>>>(x, rw, rb, cnt, tok_list, w_list);
    pad_counts<<<1, 128, 0, stream>>>(cnt, cntp, tok_list, w_list, cap);

    const dim3 sgrid(cap / 128, 20);
    if (pipelined) {
        for (int s = 0; s <= E; ++s) {
            unsigned short* hw = (s & 1) ? hb1 : hb0;
            unsigned short* hr = (s & 1) ? hb0 : hb1;
            stage_kernel<<<sgrid, 256, 0, stream>>>(
                xb, w1s, w2s, b1, b2, cntp, tok_list, w_list,
                hw, hr, out, (s < E) ? s : -1, (s > 0) ? s - 1 : -1);
        }
    } else {
        for (int e = 0; e < E; ++e) {
            stage_kernel<<<sgrid, 256, 0, stream>>>(
                xb, w1s, w2s, b1, b2, cntp, tok_list, w_list,
                hb0, hb0, out, e, -1);
            stage_kernel<<<sgrid, 256, 0, stream>>>(
                xb, w1s, w2s, b1, b2, cntp, tok_list, w_list,
                hb0, hb0, out, -1, e);
        }
    }
}